// Round 9
// baseline (105.626 us; speedup 1.0000x reference)
//
#include <hip/hip_runtime.h>
#include <math.h>

#define NT_ 365
#define NS_ 1024
#define NH_ 64
#define NG_ 32
#define NW_ 514        // NH*8 + 2
#define CH_ 64         // timesteps per chunk (= wave size)
#define NCHUNK_ 6      // ceil(365/64); tail steps are harmless dummies
#define YPAD_ 65       // padded ytile row stride: conflict-free R/W

__device__ __forceinline__ float sigmoidf(float v) {
  return 1.0f / (1.0f + expf(-v));
}

// broadcast lane l's float to all lanes (compile-time l in unrolled loops)
__device__ __forceinline__ float rdl(float v, int l) {
  return __int_as_float(__builtin_amdgcn_readlane(__float_as_int(v), l));
}

// met = (Ps, Pl, relu(Ta), E); relu folded since gm > 0
__device__ __forceinline__ float4 compute_met(float4 xv) {
  const float P = xv.x, E = xv.y, T1 = xv.z, T2 = xv.w;
  const float Ta = (T1 + T2) * 0.5f;
  float rP;
  if (T2 <= 0.0f) {
    rP = 0.0f;
  } else if (T1 >= 0.0f) {
    rP = 1.0f;
  } else {
    float r = (T1 + T2) / (T2 - T1);
    r = fminf(fmaxf(r, -0.999999f), 0.999999f);
    rP = 1.0f - acosf(r) * (1.0f / 3.1415f);
  }
  float4 m;
  m.x = (1.0f - rP) * P;
  m.y = rP * P;
  m.z = fmaxf(Ta, 0.0f);
  m.w = E;
  return m;
}

struct Gates {
  float ngm, nge, gi;         // snow stream (a = fmaf(Tz, ngm, Ps))
  float gl, mgo, kb1m, cgm;   // H/Gy stream
  float ga, c1, qb;           // y = ga*Hh + c1*M + Gy
};

// 4-STREAM INTERLEAVE = R8 split-chain x R5 two-site. Cadence law measured
// so far: ~7.5 cyc/inst with one dependence stream (R6), ~4.2 with two
// INDEPENDENT streams (R5: 2 sites, 38 insts, same 160 cyc/step). R8's two
// chains were braided (d_t feeds z_t each step) -> no gain. This kernel runs
// TWO SITES, each with the 1-step-ahead d-pipeline: four chains (S0,H0,S1,H1)
// where every adjacent instruction pair is cross-site independent ->
// predicted ~2.5-3 cyc/inst -> ~60 cyc per site-step vs ~160. Readlane met
// feed (R6), static d rotation (no scratch), zero ds_read in the walk.
__global__ __launch_bounds__(128) void waternet_scan(
    const float* __restrict__ x,     // [NT, NS, 4]
    const float* __restrict__ xc,    // [NS, NG]
    const float* __restrict__ fc_w,  // [NW, NG]
    const float* __restrict__ fc_b,  // [NW]
    float* __restrict__ out)         // [NT, NS]
{
  __shared__ float ytile[4][CH_ * YPAD_];  // 66.6 KB: per-site y rows

  const int tid  = threadIdx.x;
  const int lane = tid & 63;
  const int wv   = tid >> 6;               // 0..1
  const int ss0  = wv * 2, ss1 = ss0 + 1;  // LDS slots for this wave's sites
  const int site0 = (blockIdx.x << 2) + ss0;
  const int site1 = site0 + 1;             // adjacent: shared cache lines
  const int u0 = __builtin_amdgcn_readfirstlane(site0);
  const float4* xp  = (const float4*)x;
  const float4* wq4 = (const float4*)fc_w;

  // chunk-0 prefetch first: HBM latency hides under the gate GEMM
  float4 xc0 = xp[lane * NS_ + site0];     // t = lane
  float4 xc1 = xp[lane * NS_ + site1];

  // ---- prologue GEMM for BOTH sites, sharing every fc_w load
  float a0[8], a1[8];
#pragma unroll
  for (int k = 0; k < 8; ++k) { a0[k] = fc_b[k * NH_ + lane]; a1[k] = a0[k]; }
  float aq0 = fc_b[NW_ - 1], aq1 = aq0;

  const float4* xcq0 = (const float4*)(xc + u0 * NG_);
  const float4* xcq1 = (const float4*)(xc + (u0 + 1) * NG_);
#pragma unroll
  for (int g4 = 0; g4 < NG_ / 4; ++g4) {
    const float4 xA = xcq0[g4];
    const float4 xB = xcq1[g4];
#pragma unroll
    for (int k = 0; k < 8; ++k) {
      const float4 w = wq4[(k * NH_ + lane) * (NG_ / 4) + g4];
      a0[k] = fmaf(xA.x, w.x, a0[k]); a0[k] = fmaf(xA.y, w.y, a0[k]);
      a0[k] = fmaf(xA.z, w.z, a0[k]); a0[k] = fmaf(xA.w, w.w, a0[k]);
      a1[k] = fmaf(xB.x, w.x, a1[k]); a1[k] = fmaf(xB.y, w.y, a1[k]);
      a1[k] = fmaf(xB.z, w.z, a1[k]); a1[k] = fmaf(xB.w, w.w, a1[k]);
    }
    {
      const float4 w = wq4[(NW_ - 1) * (NG_ / 4) + g4];
      aq0 = fmaf(xA.x, w.x, aq0); aq0 = fmaf(xA.y, w.y, aq0);
      aq0 = fmaf(xA.z, w.z, aq0); aq0 = fmaf(xA.w, w.w, aq0);
      aq1 = fmaf(xB.x, w.x, aq1); aq1 = fmaf(xB.y, w.y, aq1);
      aq1 = fmaf(xB.z, w.z, aq1); aq1 = fmaf(xB.w, w.w, aq1);
    }
  }

  // ---- gates (per-lane = per hidden unit), folded constants
  auto mkgates = [&](const float a[8], float aq) -> Gates {
    Gates g;
    const float gm = expf(a[0]) + 1.0f;
    g.ngm = -gm;
    g.nge = -2.0f * sigmoidf(a[1]);
    const float go = sigmoidf(a[2]);
    g.gl  = expf(a[3] * 2.0f);
    float mx = a[4];
#pragma unroll
    for (int m2 = 32; m2 >= 1; m2 >>= 1) mx = fmaxf(mx, __shfl_xor(mx, m2, 64));
    const float ex = expf(a[4] - mx);
    float sm = ex;
#pragma unroll
    for (int m2 = 32; m2 >= 1; m2 >>= 1) sm += __shfl_xor(sm, m2, 64);
    g.ga = ex / sm;
    const float gb = sigmoidf(a[5]);
    const float kb = sigmoidf(a[6]) * 0.1f;
    g.gi   = sigmoidf(a[7]);
    g.qb   = fmaxf(aq, 0.0f) * (1.0f / NH_);
    g.mgo  = -go;
    g.kb1m = 1.0f - kb;
    g.cgm  = g.ga * kb * gb * go;              // Gy feed coeff
    g.c1   = g.ga * (go * (1.0f - gb) - 1.0f); // y = ga*Hh + c1*M + Gy
    return g;
  };
  const Gates g0 = mkgates(a0, aq0);
  const Gates g1 = mkgates(a1, aq1);

  // ---- scan state, both sites; Gy = ga*kb*G (exact rescale)
  float S0a = 0.f, H0a = 0.f, Gya = 0.f, d0A, d0B;
  float S0b = 0.f, H0b = 0.f, Gyb = 0.f, d1A, d1B;

  // met for the CURRENT chunk lives across lanes: lane = local timestep
  float4 mm0 = compute_met(xc0);
  float4 mm1 = compute_met(xc1);

  // snow stream (depth-3 chain): met(i), S_{i-1} -> d_i, S_i
  auto stg = [&](const Gates& g, const float4& mm, float& S0, int i,
                 float& dout) {
    const float Ps = rdl(mm.x, i);
    const float Pl = rdl(mm.y, i);
    const float Tz = rdl(mm.z, i);
    const float Ev = rdl(mm.w, i);
    const float a  = fmaf(Tz, g.ngm, Ps);
    const float Sn = fmaxf(S0 + a, Ps);
    const float Sm = (S0 - Sn) + Ps;
    dout = fmaf(Pl, g.gi, fmaf(Ev, g.nge, Sm));
    S0 = Sn;
  };

  // H/Gy stream (depth-4 chain): z -> fmed3 -> fmaf -> min
  auto cns = [&](const Gates& g, float& H0, float& Gy, float d, float* yp) {
    const float z  = H0 + d;
    const float Hh = fmaxf(z, 0.0f);
    const float M  = __builtin_amdgcn_fmed3f(z, 0.0f, g.gl);  // min(H, gl)
    H0 = fminf(fmaf(g.mgo, M, Hh), g.gl);
    Gy = fmaf(g.kb1m, Gy, g.cgm * M);
    *yp = Gy + fmaf(g.c1, M, g.ga * Hh);
  };

  float*       yw0 = &ytile[ss0][lane];
  float*       yw1 = &ytile[ss1][lane];
  const float* yr0 = &ytile[ss0][lane * YPAD_];
  const float* yr1 = &ytile[ss1][lane * YPAD_];

  // pipeline fill: d for global step 0, both sites
  stg(g0, mm0, S0a, 0, d0A);
  stg(g1, mm1, S0b, 0, d1A);

#pragma unroll 1   // keep body I-cache resident across 6 iterations
  for (int c = 0; c < NCHUNK_; ++c) {
    // prefetch chunk c+1 from HBM (clamped dummy tail) — in flight all chunk
    int tn = (c + 1) * CH_ + lane;
    tn = (tn < NT_) ? tn : (NT_ - 1);
    const float4 xn0 = xp[tn * NS_ + site0];
    const float4 xn1 = xp[tn * NS_ + site1];

    // ---- 64 steps x 2 sites: every adjacent op pair is cross-site
    // independent -> 4 chains (S0,H0,S1,H1) fill each other's dep gaps.
#pragma unroll
    for (int j2 = 0; j2 < 31; ++j2) {
      const int u = 2 * j2;
      cns(g0, H0a, Gya, d0A, yw0 + u * YPAD_);
      cns(g1, H0b, Gyb, d1A, yw1 + u * YPAD_);
      stg(g0, mm0, S0a, u + 1, d0B);
      stg(g1, mm1, S0b, u + 1, d1B);
      cns(g0, H0a, Gya, d0B, yw0 + (u + 1) * YPAD_);
      cns(g1, H0b, Gyb, d1B, yw1 + (u + 1) * YPAD_);
      stg(g0, mm0, S0a, u + 2, d0A);
      stg(g1, mm1, S0b, u + 2, d1A);
    }
    cns(g0, H0a, Gya, d0A, yw0 + 62 * YPAD_);   // steps 62, 63
    cns(g1, H0b, Gyb, d1A, yw1 + 62 * YPAD_);
    stg(g0, mm0, S0a, 63, d0B);
    stg(g1, mm1, S0b, 63, d1B);
    cns(g0, H0a, Gya, d0B, yw0 + 63 * YPAD_);
    cns(g1, H0b, Gyb, d1B, yw1 + 63 * YPAD_);

    // ---- transposed reduction, both sites (bank=(t'+h)%32, conflict-free);
    // same-wave DS ordering makes the writes above visible without a barrier
    float rA0 = 0.f, rA1 = 0.f, rA2 = 0.f, rA3 = 0.f;
    float rB0 = 0.f, rB1 = 0.f, rB2 = 0.f, rB3 = 0.f;
#pragma unroll
    for (int h = 0; h < CH_; h += 4) {
      rA0 += yr0[h + 0]; rA1 += yr0[h + 1];
      rA2 += yr0[h + 2]; rA3 += yr0[h + 3];
      rB0 += yr1[h + 0]; rB1 += yr1[h + 1];
      rB2 += yr1[h + 2]; rB3 += yr1[h + 3];
    }
    const int t_out = c * CH_ + lane;
    if (t_out < NT_) {
      out[t_out * NS_ + site0] = ((rA0 + rA1) + (rA2 + rA3)) + g0.qb;
      out[t_out * NS_ + site1] = ((rB0 + rB1) + (rB2 + rB3)) + g1.qb;
    }

    // chunk top for c+1: new met into lane-regs, then the deferred stage(0)
    if (c + 1 < NCHUNK_) {
      mm0 = compute_met(xn0);
      mm1 = compute_met(xn1);
      stg(g0, mm0, S0a, 0, d0A);
      stg(g1, mm1, S0b, 0, d1A);
    }
  }
}

extern "C" void kernel_launch(void* const* d_in, const int* in_sizes, int n_in,
                              void* d_out, int out_size, void* d_ws, size_t ws_size,
                              hipStream_t stream) {
  const float* x    = (const float*)d_in[0];
  const float* xc   = (const float*)d_in[1];
  const float* fc_w = (const float*)d_in[2];
  const float* fc_b = (const float*)d_in[3];
  float* out = (float*)d_out;

  // 1024 sites, 2 sites per wave, 2 waves per block -> 256 blocks of 128
  // threads, 66.6 KB LDS. All 512 waves resident (<=1 wave/SIMD): the
  // interleaving happens INSIDE each wave across 4 independent chains.
  hipLaunchKernelGGL(waternet_scan, dim3(NS_ / 4), dim3(128), 0, stream,
                     x, xc, fc_w, fc_b, out);
}